// Round 6
// baseline (254.919 us; speedup 1.0000x reference)
//
#include <hip/hip_runtime.h>

typedef float  f32x2  __attribute__((ext_vector_type(2)));
typedef float  f32x4  __attribute__((ext_vector_type(4)));
typedef float  f32x16 __attribute__((ext_vector_type(16)));
typedef short  s16x4  __attribute__((ext_vector_type(4)));
typedef short  s16x8  __attribute__((ext_vector_type(8)));
typedef unsigned int u32x2 __attribute__((ext_vector_type(2)));

__device__ __forceinline__ unsigned f2bf(float f) {
    unsigned u = __builtin_bit_cast(unsigned, f);
    u += 0x7FFFu + ((u >> 16) & 1u);   // RNE
    return u >> 16;
}
__device__ __forceinline__ s16x4 pack4(float a, float b, float c, float d) {
    u32x2 u;
    u[0] = f2bf(a) | (f2bf(b) << 16);
    u[1] = f2bf(c) | (f2bf(d) << 16);
    return __builtin_bit_cast(s16x4, u);
}
__device__ __forceinline__ s16x4 pack4v(f32x4 v) { return pack4(v[0], v[1], v[2], v[3]); }
__device__ __forceinline__ s16x4 lo4(s16x8 v) { return __builtin_shufflevector(v, v, 0, 1, 2, 3); }
__device__ __forceinline__ s16x4 hi4(s16x8 v) { return __builtin_shufflevector(v, v, 4, 5, 6, 7); }

// ---------------------------------------------------------------------------
// Node MLP: P = relu(relu(X W1^T + b1) W2^T + b2) Wm^T (+ bm), bf16 out,
// standard channel layout P[node*32 + ch]. One wave per 32-node tile,
// 4 consecutive tiles per wave (weight-fragment setup amortized).
// ---------------------------------------------------------------------------
__device__ __forceinline__ void node_body(
    const float* __restrict__ X,
    const float* __restrict__ W1, const float* __restrict__ b1,
    const float* __restrict__ W2, const float* __restrict__ b2,
    const float* __restrict__ Wm, const float* __restrict__ bm,
    unsigned short* __restrict__ outp, int N, int tile0)
{
    const int lane = threadIdx.x & 63;
    const int g = lane >> 5, m = lane & 31;
    const int ntile = (N + 31) >> 5;
    if (tile0 >= ntile) return;

    s16x4 a1[4], a2[4], am[4];
#pragma unroll
    for (int q = 0; q < 4; ++q) {
        const float* p1 = W1 + m * 32 + 8 * q + 4 * g;
        a1[q] = pack4(p1[0], p1[1], p1[2], p1[3]);
        const float* p2 = W2 + m * 32 + 8 * q + 4 * g;
        a2[q] = pack4(p2[0], p2[1], p2[2], p2[3]);
        const float* pm = Wm + m * 96 + 8 * q + 4 * g;
        am[q] = pack4(pm[0], pm[1], pm[2], pm[3]);
    }
    f32x16 f1, f2, f3;
#pragma unroll
    for (int r = 0; r < 16; ++r) {
        int ch = (r & 3) + 8 * (r >> 2) + 4 * g;
        f1[r] = b1[ch];
        f2[r] = b2[ch];
        f3[r] = bm ? bm[ch] : 0.f;
    }

#pragma unroll
    for (int k = 0; k < 4; ++k) {
        const int tile = tile0 + k;
        if (tile >= ntile) break;
        const int node0 = tile * 32 + m;
        const int node = node0 < N ? node0 : N - 1;

        s16x4 bX[4];
#pragma unroll
        for (int q = 0; q < 4; ++q) {
            f32x4 v = *reinterpret_cast<const f32x4*>(X + (size_t)node * 32 + 8 * q + 4 * g);
            bX[q] = pack4v(v);
        }
        f32x16 acc = f1;
#pragma unroll
        for (int q = 0; q < 4; ++q) acc = __builtin_amdgcn_mfma_f32_32x32x8bf16_1k(a1[q], bX[q], acc, 0, 0, 0);
        s16x4 bH[4];
#pragma unroll
        for (int q = 0; q < 4; ++q)
            bH[q] = pack4(fmaxf(acc[4*q+0], 0.f), fmaxf(acc[4*q+1], 0.f),
                          fmaxf(acc[4*q+2], 0.f), fmaxf(acc[4*q+3], 0.f));
        acc = f2;
#pragma unroll
        for (int q = 0; q < 4; ++q) acc = __builtin_amdgcn_mfma_f32_32x32x8bf16_1k(a2[q], bH[q], acc, 0, 0, 0);
#pragma unroll
        for (int q = 0; q < 4; ++q)
            bH[q] = pack4(fmaxf(acc[4*q+0], 0.f), fmaxf(acc[4*q+1], 0.f),
                          fmaxf(acc[4*q+2], 0.f), fmaxf(acc[4*q+3], 0.f));
        acc = f3;
#pragma unroll
        for (int q = 0; q < 4; ++q) acc = __builtin_amdgcn_mfma_f32_32x32x8bf16_1k(am[q], bH[q], acc, 0, 0, 0);

        if (node0 < N) {
#pragma unroll
            for (int q = 0; q < 4; ++q) {
                s16x4 o = pack4(acc[4*q+0], acc[4*q+1], acc[4*q+2], acc[4*q+3]);
                *reinterpret_cast<s16x4*>(outp + (size_t)node0 * 32 + 8 * q + 4 * g) = o;
            }
        }
    }
}

__global__ __launch_bounds__(256) void nodes_kernel(
    const float* __restrict__ var_f, const float* __restrict__ con_f,
    const float* __restrict__ Wv1, const float* __restrict__ bv1,
    const float* __restrict__ Wv2, const float* __restrict__ bv2,
    const float* __restrict__ Wc1, const float* __restrict__ bc1,
    const float* __restrict__ Wc2, const float* __restrict__ bc2,
    const float* __restrict__ We1, const float* __restrict__ be1,
    unsigned short* __restrict__ pv, unsigned short* __restrict__ pc,
    int nV, int nC, int wavesV)
{
    const int wvg = (blockIdx.x * blockDim.x + threadIdx.x) >> 6;
    if (wvg < wavesV) {
        node_body(var_f, Wv1, bv1, Wv2, bv2, We1 + 32, be1, pv, nV, wvg * 4);
    } else {
        node_body(con_f, Wc1, bc1, Wc2, bc2, We1 + 64, nullptr, pc, nC,
                  (wvg - wavesV) * 4);
    }
}

// ---------------------------------------------------------------------------
// Edge kernel: wave-independent, no barriers, full depth-1 software pipeline
// (Ef/gathers/idx all issued one iteration ahead). This round: max residency —
// __launch_bounds__(256,8) caps VGPR at 64 (R5 used 52), grid 2048 = exactly
// 8 blocks/CU = 32 waves/CU (HW max), LDS 8*17.4KB = 139KB < 160KB.
// ---------------------------------------------------------------------------
__global__ __launch_bounds__(256, 8) void edge_kernel(
    const float* __restrict__ Ef, const int* __restrict__ idx,
    const unsigned short* __restrict__ pv, const unsigned short* __restrict__ pc,
    const float* __restrict__ We1, const float* __restrict__ We2,
    const float* __restrict__ be2,
    float* __restrict__ out, int nE)
{
    __shared__ float ldso[4 * 1088];          // 4 waves * 32 rows * stride 34
    const int lane = threadIdx.x & 63;
    const int wv = threadIdx.x >> 6;
    const int g = lane >> 5, n = lane & 31;
    float* ldsw = ldso + wv * 1088;

    // A fragments. Layer 1: ch1(q,g,j)=16g+4q+j; layer 2: ch2=8q+4g+j.
    s16x4 aW1[4], aI[4], aW2[4];
#pragma unroll
    for (int q = 0; q < 4; ++q) {
        const float* p = We1 + n * 96 + 16 * g + 4 * q;
        aW1[q] = pack4(p[0], p[1], p[2], p[3]);
        s16x4 r;
#pragma unroll
        for (int j = 0; j < 4; ++j) r[j] = (short)((16 * g + 4 * q + j == n) ? 0x3F80 : 0);
        aI[q] = r;
        const float* p2 = We2 + n * 32 + 8 * q + 4 * g;
        aW2[q] = pack4(p2[0], p2[1], p2[2], p2[3]);
    }
    // be2 as one extra MFMA: A[:,0]=be2, B[0,:]=1
    s16x4 aB2 = {}, bOne = {};
    if (g == 0) {
        aB2[0] = (short)f2bf(be2[n]);
        bOne[0] = (short)0x3F80;
    }

    const int ntile = nE >> 5;
    const int nw = (gridDim.x * blockDim.x) >> 6;
    int t = (blockIdx.x * blockDim.x + threadIdx.x) >> 6;
    if (t >= ntile) return;

    // ---- prologue: fill stage for tile t, plus idx for t+nw ----
    int e0 = t * 32 + n;
    int ia0 = idx[e0], ia1 = idx[nE + e0];
    const float* efp = Ef + (size_t)e0 * 32 + 16 * g;
    f32x4 ce0 = *reinterpret_cast<const f32x4*>(efp + 0);
    f32x4 ce1 = *reinterpret_cast<const f32x4*>(efp + 4);
    f32x4 ce2 = *reinterpret_cast<const f32x4*>(efp + 8);
    f32x4 ce3 = *reinterpret_cast<const f32x4*>(efp + 12);
    const unsigned short* pvr0 = pv + (size_t)ia0 * 32 + 16 * g;
    const unsigned short* pcr0 = pc + (size_t)ia1 * 32 + 16 * g;
    s16x8 cv0 = *reinterpret_cast<const s16x8*>(pvr0);
    s16x8 cv1 = *reinterpret_cast<const s16x8*>(pvr0 + 8);
    s16x8 cc0 = *reinterpret_cast<const s16x8*>(pcr0);
    s16x8 cc1 = *reinterpret_cast<const s16x8*>(pcr0 + 8);
    {
        int t1 = (t + nw < ntile) ? t + nw : t;
        int e1 = t1 * 32 + n;
        ia0 = idx[e1]; ia1 = idx[nE + e1];   // idx of tile t+nw
    }
    int ib0 = ia0, ib1 = ia1;

    while (true) {
        const int tn = t + nw;
        const int tc = tn < ntile ? tn : t;

        // ---- issue stage(t+nw): Ef ----
        const float* efpn = Ef + (size_t)(tc * 32 + n) * 32 + 16 * g;
        f32x4 ne0 = *reinterpret_cast<const f32x4*>(efpn + 0);
        f32x4 ne1 = *reinterpret_cast<const f32x4*>(efpn + 4);
        f32x4 ne2 = *reinterpret_cast<const f32x4*>(efpn + 8);
        f32x4 ne3 = *reinterpret_cast<const f32x4*>(efpn + 12);
        // ---- issue stage(t+nw): gathers (idx already resident) ----
        const unsigned short* pvn = pv + (size_t)ib0 * 32 + 16 * g;
        const unsigned short* pcn = pc + (size_t)ib1 * 32 + 16 * g;
        s16x8 nv0 = *reinterpret_cast<const s16x8*>(pvn);
        s16x8 nv1 = *reinterpret_cast<const s16x8*>(pvn + 8);
        s16x8 nc0 = *reinterpret_cast<const s16x8*>(pcn);
        s16x8 nc1 = *reinterpret_cast<const s16x8*>(pcn + 8);
        // ---- issue idx(t+2*nw) ----
        int t2 = (tn + nw < ntile) ? tn + nw : tc;
        int e2 = t2 * 32 + n;
        int ic0 = idx[e2], ic1 = idx[nE + e2];

        // ---- compute tile t from current-stage registers ----
        f32x16 acc = {};
        {
            s16x4 bE0 = pack4v(ce0), bE1 = pack4v(ce1), bE2 = pack4v(ce2), bE3 = pack4v(ce3);
            acc = __builtin_amdgcn_mfma_f32_32x32x8bf16_1k(aW1[0], bE0, acc, 0, 0, 0);
            acc = __builtin_amdgcn_mfma_f32_32x32x8bf16_1k(aW1[1], bE1, acc, 0, 0, 0);
            acc = __builtin_amdgcn_mfma_f32_32x32x8bf16_1k(aW1[2], bE2, acc, 0, 0, 0);
            acc = __builtin_amdgcn_mfma_f32_32x32x8bf16_1k(aW1[3], bE3, acc, 0, 0, 0);
        }
        acc = __builtin_amdgcn_mfma_f32_32x32x8bf16_1k(aI[0], lo4(cv0), acc, 0, 0, 0);
        acc = __builtin_amdgcn_mfma_f32_32x32x8bf16_1k(aI[1], hi4(cv0), acc, 0, 0, 0);
        acc = __builtin_amdgcn_mfma_f32_32x32x8bf16_1k(aI[2], lo4(cv1), acc, 0, 0, 0);
        acc = __builtin_amdgcn_mfma_f32_32x32x8bf16_1k(aI[3], hi4(cv1), acc, 0, 0, 0);
        acc = __builtin_amdgcn_mfma_f32_32x32x8bf16_1k(aI[0], lo4(cc0), acc, 0, 0, 0);
        acc = __builtin_amdgcn_mfma_f32_32x32x8bf16_1k(aI[1], hi4(cc0), acc, 0, 0, 0);
        acc = __builtin_amdgcn_mfma_f32_32x32x8bf16_1k(aI[2], lo4(cc1), acc, 0, 0, 0);
        acc = __builtin_amdgcn_mfma_f32_32x32x8bf16_1k(aI[3], hi4(cc1), acc, 0, 0, 0);

        s16x4 bH[4];
#pragma unroll
        for (int q = 0; q < 4; ++q)
            bH[q] = pack4(fmaxf(acc[4*q+0], 0.f), fmaxf(acc[4*q+1], 0.f),
                          fmaxf(acc[4*q+2], 0.f), fmaxf(acc[4*q+3], 0.f));

        f32x16 acc2 = {};
        acc2 = __builtin_amdgcn_mfma_f32_32x32x8bf16_1k(aB2, bOne, acc2, 0, 0, 0);
#pragma unroll
        for (int q = 0; q < 4; ++q)
            acc2 = __builtin_amdgcn_mfma_f32_32x32x8bf16_1k(aW2[q], bH[q], acc2, 0, 0, 0);

        // ---- store: wave-private LDS transpose (stride 34), then NT stores ----
        {
            float* orow = ldsw + n * 34;
#pragma unroll
            for (int q = 0; q < 4; ++q) {
                f32x2 lo; lo[0] = acc2[4*q+0]; lo[1] = acc2[4*q+1];
                f32x2 hi; hi[0] = acc2[4*q+2]; hi[1] = acc2[4*q+3];
                *reinterpret_cast<f32x2*>(orow + 8 * q + 4 * g)     = lo;
                *reinterpret_cast<f32x2*>(orow + 8 * q + 4 * g + 2) = hi;
            }
            float* obase = out + (size_t)t * 1024;
#pragma unroll
            for (int p = 0; p < 4; ++p) {
                int li = p * 256 + lane * 4;
                int row = li >> 5, col = li & 31;
                const float* s = ldsw + row * 34 + col;
                f32x2 lo = *reinterpret_cast<const f32x2*>(s);
                f32x2 hi = *reinterpret_cast<const f32x2*>(s + 2);
                f32x4 v; v[0] = lo[0]; v[1] = lo[1]; v[2] = hi[0]; v[3] = hi[1];
                __builtin_nontemporal_store(v, reinterpret_cast<f32x4*>(obase + li));
            }
        }

        if (tn >= ntile) break;
        t = tn;
        ce0 = ne0; ce1 = ne1; ce2 = ne2; ce3 = ne3;
        cv0 = nv0; cv1 = nv1; cc0 = nc0; cc1 = nc1;
        ib0 = ic0; ib1 = ic1;
    }
}

extern "C" void kernel_launch(void* const* d_in, const int* in_sizes, int n_in,
                              void* d_out, int out_size, void* d_ws, size_t ws_size,
                              hipStream_t stream) {
    const float* var_f = (const float*)d_in[0];
    const float* con_f = (const float*)d_in[1];
    const float* Ef    = (const float*)d_in[2];
    const int*   idx   = (const int*)d_in[3];
    const float* Wv1 = (const float*)d_in[4];
    const float* bv1 = (const float*)d_in[5];
    const float* Wv2 = (const float*)d_in[6];
    const float* bv2 = (const float*)d_in[7];
    const float* Wc1 = (const float*)d_in[8];
    const float* bc1 = (const float*)d_in[9];
    const float* Wc2 = (const float*)d_in[10];
    const float* bc2 = (const float*)d_in[11];
    const float* We1 = (const float*)d_in[12];
    const float* be1 = (const float*)d_in[13];
    const float* We2 = (const float*)d_in[14];
    const float* be2 = (const float*)d_in[15];
    float* out = (float*)d_out;

    const int nV = in_sizes[0] / 32;
    const int nC = in_sizes[1] / 32;
    const int nE = in_sizes[2] / 32;

    unsigned short* pv = (unsigned short*)d_ws;
    unsigned short* pc = pv + (size_t)nV * 32;

    const int wavesV = (((nV + 31) >> 5) + 3) >> 2;
    const int wavesC = (((nC + 31) >> 5) + 3) >> 2;
    const int nodeBlocks = (wavesV + wavesC + 3) / 4;
    nodes_kernel<<<nodeBlocks, 256, 0, stream>>>(
        var_f, con_f, Wv1, bv1, Wv2, bv2, Wc1, bc1, Wc2, bc2,
        We1, be1, pv, pc, nV, nC, wavesV);

    edge_kernel<<<2048, 256, 0, stream>>>(Ef, idx, pv, pc, We1, We2, be2, out, nE);
}

// Round 7
// 175.019 us; speedup vs baseline: 1.4565x; 1.4565x over previous
//
#include <hip/hip_runtime.h>

typedef float  f32x2  __attribute__((ext_vector_type(2)));
typedef float  f32x4  __attribute__((ext_vector_type(4)));
typedef float  f32x16 __attribute__((ext_vector_type(16)));
typedef short  s16x4  __attribute__((ext_vector_type(4)));
typedef short  s16x8  __attribute__((ext_vector_type(8)));
typedef unsigned int u32x2 __attribute__((ext_vector_type(2)));

__device__ __forceinline__ unsigned f2bf(float f) {
    unsigned u = __builtin_bit_cast(unsigned, f);
    u += 0x7FFFu + ((u >> 16) & 1u);   // RNE
    return u >> 16;
}
__device__ __forceinline__ s16x4 pack4(float a, float b, float c, float d) {
    u32x2 u;
    u[0] = f2bf(a) | (f2bf(b) << 16);
    u[1] = f2bf(c) | (f2bf(d) << 16);
    return __builtin_bit_cast(s16x4, u);
}
__device__ __forceinline__ s16x4 pack4v(f32x4 v) { return pack4(v[0], v[1], v[2], v[3]); }
__device__ __forceinline__ s16x4 lo4(s16x8 v) { return __builtin_shufflevector(v, v, 0, 1, 2, 3); }
__device__ __forceinline__ s16x4 hi4(s16x8 v) { return __builtin_shufflevector(v, v, 4, 5, 6, 7); }

// ---------------------------------------------------------------------------
// Node MLP: P = relu(relu(X W1^T + b1) W2^T + b2) Wm^T (+ bm), bf16 out,
// standard channel layout P[node*32 + ch]. One wave per 32-node tile,
// 4 consecutive tiles per wave (weight-fragment setup amortized).
// ---------------------------------------------------------------------------
__device__ __forceinline__ void node_body(
    const float* __restrict__ X,
    const float* __restrict__ W1, const float* __restrict__ b1,
    const float* __restrict__ W2, const float* __restrict__ b2,
    const float* __restrict__ Wm, const float* __restrict__ bm,
    unsigned short* __restrict__ outp, int N, int tile0)
{
    const int lane = threadIdx.x & 63;
    const int g = lane >> 5, m = lane & 31;
    const int ntile = (N + 31) >> 5;
    if (tile0 >= ntile) return;

    s16x4 a1[4], a2[4], am[4];
#pragma unroll
    for (int q = 0; q < 4; ++q) {
        const float* p1 = W1 + m * 32 + 8 * q + 4 * g;
        a1[q] = pack4(p1[0], p1[1], p1[2], p1[3]);
        const float* p2 = W2 + m * 32 + 8 * q + 4 * g;
        a2[q] = pack4(p2[0], p2[1], p2[2], p2[3]);
        const float* pm = Wm + m * 96 + 8 * q + 4 * g;
        am[q] = pack4(pm[0], pm[1], pm[2], pm[3]);
    }
    f32x16 f1, f2, f3;
#pragma unroll
    for (int r = 0; r < 16; ++r) {
        int ch = (r & 3) + 8 * (r >> 2) + 4 * g;
        f1[r] = b1[ch];
        f2[r] = b2[ch];
        f3[r] = bm ? bm[ch] : 0.f;
    }

#pragma unroll
    for (int k = 0; k < 4; ++k) {
        const int tile = tile0 + k;
        if (tile >= ntile) break;
        const int node0 = tile * 32 + m;
        const int node = node0 < N ? node0 : N - 1;

        s16x4 bX[4];
#pragma unroll
        for (int q = 0; q < 4; ++q) {
            f32x4 v = *reinterpret_cast<const f32x4*>(X + (size_t)node * 32 + 8 * q + 4 * g);
            bX[q] = pack4v(v);
        }
        f32x16 acc = f1;
#pragma unroll
        for (int q = 0; q < 4; ++q) acc = __builtin_amdgcn_mfma_f32_32x32x8bf16_1k(a1[q], bX[q], acc, 0, 0, 0);
        s16x4 bH[4];
#pragma unroll
        for (int q = 0; q < 4; ++q)
            bH[q] = pack4(fmaxf(acc[4*q+0], 0.f), fmaxf(acc[4*q+1], 0.f),
                          fmaxf(acc[4*q+2], 0.f), fmaxf(acc[4*q+3], 0.f));
        acc = f2;
#pragma unroll
        for (int q = 0; q < 4; ++q) acc = __builtin_amdgcn_mfma_f32_32x32x8bf16_1k(a2[q], bH[q], acc, 0, 0, 0);
#pragma unroll
        for (int q = 0; q < 4; ++q)
            bH[q] = pack4(fmaxf(acc[4*q+0], 0.f), fmaxf(acc[4*q+1], 0.f),
                          fmaxf(acc[4*q+2], 0.f), fmaxf(acc[4*q+3], 0.f));
        acc = f3;
#pragma unroll
        for (int q = 0; q < 4; ++q) acc = __builtin_amdgcn_mfma_f32_32x32x8bf16_1k(am[q], bH[q], acc, 0, 0, 0);

        if (node0 < N) {
#pragma unroll
            for (int q = 0; q < 4; ++q) {
                s16x4 o = pack4(acc[4*q+0], acc[4*q+1], acc[4*q+2], acc[4*q+3]);
                *reinterpret_cast<s16x4*>(outp + (size_t)node0 * 32 + 8 * q + 4 * g) = o;
            }
        }
    }
}

__global__ __launch_bounds__(256) void nodes_kernel(
    const float* __restrict__ var_f, const float* __restrict__ con_f,
    const float* __restrict__ Wv1, const float* __restrict__ bv1,
    const float* __restrict__ Wv2, const float* __restrict__ bv2,
    const float* __restrict__ Wc1, const float* __restrict__ bc1,
    const float* __restrict__ Wc2, const float* __restrict__ bc2,
    const float* __restrict__ We1, const float* __restrict__ be1,
    unsigned short* __restrict__ pv, unsigned short* __restrict__ pc,
    int nV, int nC, int wavesV)
{
    const int wvg = (blockIdx.x * blockDim.x + threadIdx.x) >> 6;
    if (wvg < wavesV) {
        node_body(var_f, Wv1, bv1, Wv2, bv2, We1 + 32, be1, pv, nV, wvg * 4);
    } else {
        node_body(con_f, Wc1, bc1, Wc2, bc2, We1 + 64, nullptr, pc, nC,
                  (wvg - wavesV) * 4);
    }
}

// ---------------------------------------------------------------------------
// Edge kernel: wave-independent, no barriers, full depth-1 software pipeline
// (Ef/gathers/idx all issued one iteration ahead). R7: identical to R5 except
// grid 2304 (9 blocks/CU; actual residency 8-9 blocks = 32 waves/CU HW cap,
// LDS 9*17.4=156.7KB<160, VGPR 52 -> 9 waves/SIMD ok). launch_bounds(256,4)
// keeps the allocator at R5's 52 VGPR — the R6 spill disaster came from (,8).
// ---------------------------------------------------------------------------
__global__ __launch_bounds__(256, 4) void edge_kernel(
    const float* __restrict__ Ef, const int* __restrict__ idx,
    const unsigned short* __restrict__ pv, const unsigned short* __restrict__ pc,
    const float* __restrict__ We1, const float* __restrict__ We2,
    const float* __restrict__ be2,
    float* __restrict__ out, int nE)
{
    __shared__ float ldso[4 * 1088];          // 4 waves * 32 rows * stride 34
    const int lane = threadIdx.x & 63;
    const int wv = threadIdx.x >> 6;
    const int g = lane >> 5, n = lane & 31;
    float* ldsw = ldso + wv * 1088;

    // A fragments. Layer 1: ch1(q,g,j)=16g+4q+j; layer 2: ch2=8q+4g+j.
    s16x4 aW1[4], aI[4], aW2[4];
#pragma unroll
    for (int q = 0; q < 4; ++q) {
        const float* p = We1 + n * 96 + 16 * g + 4 * q;
        aW1[q] = pack4(p[0], p[1], p[2], p[3]);
        s16x4 r;
#pragma unroll
        for (int j = 0; j < 4; ++j) r[j] = (short)((16 * g + 4 * q + j == n) ? 0x3F80 : 0);
        aI[q] = r;
        const float* p2 = We2 + n * 32 + 8 * q + 4 * g;
        aW2[q] = pack4(p2[0], p2[1], p2[2], p2[3]);
    }
    // be2 as one extra MFMA: A[:,0]=be2, B[0,:]=1
    s16x4 aB2 = {}, bOne = {};
    if (g == 0) {
        aB2[0] = (short)f2bf(be2[n]);
        bOne[0] = (short)0x3F80;
    }

    const int ntile = nE >> 5;
    const int nw = (gridDim.x * blockDim.x) >> 6;
    int t = (blockIdx.x * blockDim.x + threadIdx.x) >> 6;
    if (t >= ntile) return;

    // ---- prologue: fill stage for tile t, plus idx for t+nw ----
    int e0 = t * 32 + n;
    int ia0 = idx[e0], ia1 = idx[nE + e0];
    const float* efp = Ef + (size_t)e0 * 32 + 16 * g;
    f32x4 ce0 = *reinterpret_cast<const f32x4*>(efp + 0);
    f32x4 ce1 = *reinterpret_cast<const f32x4*>(efp + 4);
    f32x4 ce2 = *reinterpret_cast<const f32x4*>(efp + 8);
    f32x4 ce3 = *reinterpret_cast<const f32x4*>(efp + 12);
    const unsigned short* pvr0 = pv + (size_t)ia0 * 32 + 16 * g;
    const unsigned short* pcr0 = pc + (size_t)ia1 * 32 + 16 * g;
    s16x8 cv0 = *reinterpret_cast<const s16x8*>(pvr0);
    s16x8 cv1 = *reinterpret_cast<const s16x8*>(pvr0 + 8);
    s16x8 cc0 = *reinterpret_cast<const s16x8*>(pcr0);
    s16x8 cc1 = *reinterpret_cast<const s16x8*>(pcr0 + 8);
    {
        int t1 = (t + nw < ntile) ? t + nw : t;
        int e1 = t1 * 32 + n;
        ia0 = idx[e1]; ia1 = idx[nE + e1];   // idx of tile t+nw
    }
    int ib0 = ia0, ib1 = ia1;

    while (true) {
        const int tn = t + nw;
        const int tc = tn < ntile ? tn : t;

        // ---- issue stage(t+nw): Ef ----
        const float* efpn = Ef + (size_t)(tc * 32 + n) * 32 + 16 * g;
        f32x4 ne0 = *reinterpret_cast<const f32x4*>(efpn + 0);
        f32x4 ne1 = *reinterpret_cast<const f32x4*>(efpn + 4);
        f32x4 ne2 = *reinterpret_cast<const f32x4*>(efpn + 8);
        f32x4 ne3 = *reinterpret_cast<const f32x4*>(efpn + 12);
        // ---- issue stage(t+nw): gathers (idx already resident) ----
        const unsigned short* pvn = pv + (size_t)ib0 * 32 + 16 * g;
        const unsigned short* pcn = pc + (size_t)ib1 * 32 + 16 * g;
        s16x8 nv0 = *reinterpret_cast<const s16x8*>(pvn);
        s16x8 nv1 = *reinterpret_cast<const s16x8*>(pvn + 8);
        s16x8 nc0 = *reinterpret_cast<const s16x8*>(pcn);
        s16x8 nc1 = *reinterpret_cast<const s16x8*>(pcn + 8);
        // ---- issue idx(t+2*nw) ----
        int t2 = (tn + nw < ntile) ? tn + nw : tc;
        int e2 = t2 * 32 + n;
        int ic0 = idx[e2], ic1 = idx[nE + e2];

        // ---- compute tile t from current-stage registers ----
        f32x16 acc = {};
        {
            s16x4 bE0 = pack4v(ce0), bE1 = pack4v(ce1), bE2 = pack4v(ce2), bE3 = pack4v(ce3);
            acc = __builtin_amdgcn_mfma_f32_32x32x8bf16_1k(aW1[0], bE0, acc, 0, 0, 0);
            acc = __builtin_amdgcn_mfma_f32_32x32x8bf16_1k(aW1[1], bE1, acc, 0, 0, 0);
            acc = __builtin_amdgcn_mfma_f32_32x32x8bf16_1k(aW1[2], bE2, acc, 0, 0, 0);
            acc = __builtin_amdgcn_mfma_f32_32x32x8bf16_1k(aW1[3], bE3, acc, 0, 0, 0);
        }
        acc = __builtin_amdgcn_mfma_f32_32x32x8bf16_1k(aI[0], lo4(cv0), acc, 0, 0, 0);
        acc = __builtin_amdgcn_mfma_f32_32x32x8bf16_1k(aI[1], hi4(cv0), acc, 0, 0, 0);
        acc = __builtin_amdgcn_mfma_f32_32x32x8bf16_1k(aI[2], lo4(cv1), acc, 0, 0, 0);
        acc = __builtin_amdgcn_mfma_f32_32x32x8bf16_1k(aI[3], hi4(cv1), acc, 0, 0, 0);
        acc = __builtin_amdgcn_mfma_f32_32x32x8bf16_1k(aI[0], lo4(cc0), acc, 0, 0, 0);
        acc = __builtin_amdgcn_mfma_f32_32x32x8bf16_1k(aI[1], hi4(cc0), acc, 0, 0, 0);
        acc = __builtin_amdgcn_mfma_f32_32x32x8bf16_1k(aI[2], lo4(cc1), acc, 0, 0, 0);
        acc = __builtin_amdgcn_mfma_f32_32x32x8bf16_1k(aI[3], hi4(cc1), acc, 0, 0, 0);

        s16x4 bH[4];
#pragma unroll
        for (int q = 0; q < 4; ++q)
            bH[q] = pack4(fmaxf(acc[4*q+0], 0.f), fmaxf(acc[4*q+1], 0.f),
                          fmaxf(acc[4*q+2], 0.f), fmaxf(acc[4*q+3], 0.f));

        f32x16 acc2 = {};
        acc2 = __builtin_amdgcn_mfma_f32_32x32x8bf16_1k(aB2, bOne, acc2, 0, 0, 0);
#pragma unroll
        for (int q = 0; q < 4; ++q)
            acc2 = __builtin_amdgcn_mfma_f32_32x32x8bf16_1k(aW2[q], bH[q], acc2, 0, 0, 0);

        // ---- store: wave-private LDS transpose (stride 34), then NT stores ----
        {
            float* orow = ldsw + n * 34;
#pragma unroll
            for (int q = 0; q < 4; ++q) {
                f32x2 lo; lo[0] = acc2[4*q+0]; lo[1] = acc2[4*q+1];
                f32x2 hi; hi[0] = acc2[4*q+2]; hi[1] = acc2[4*q+3];
                *reinterpret_cast<f32x2*>(orow + 8 * q + 4 * g)     = lo;
                *reinterpret_cast<f32x2*>(orow + 8 * q + 4 * g + 2) = hi;
            }
            float* obase = out + (size_t)t * 1024;
#pragma unroll
            for (int p = 0; p < 4; ++p) {
                int li = p * 256 + lane * 4;
                int row = li >> 5, col = li & 31;
                const float* s = ldsw + row * 34 + col;
                f32x2 lo = *reinterpret_cast<const f32x2*>(s);
                f32x2 hi = *reinterpret_cast<const f32x2*>(s + 2);
                f32x4 v; v[0] = lo[0]; v[1] = lo[1]; v[2] = hi[0]; v[3] = hi[1];
                __builtin_nontemporal_store(v, reinterpret_cast<f32x4*>(obase + li));
            }
        }

        if (tn >= ntile) break;
        t = tn;
        ce0 = ne0; ce1 = ne1; ce2 = ne2; ce3 = ne3;
        cv0 = nv0; cv1 = nv1; cc0 = nc0; cc1 = nc1;
        ib0 = ic0; ib1 = ic1;
    }
}

extern "C" void kernel_launch(void* const* d_in, const int* in_sizes, int n_in,
                              void* d_out, int out_size, void* d_ws, size_t ws_size,
                              hipStream_t stream) {
    const float* var_f = (const float*)d_in[0];
    const float* con_f = (const float*)d_in[1];
    const float* Ef    = (const float*)d_in[2];
    const int*   idx   = (const int*)d_in[3];
    const float* Wv1 = (const float*)d_in[4];
    const float* bv1 = (const float*)d_in[5];
    const float* Wv2 = (const float*)d_in[6];
    const float* bv2 = (const float*)d_in[7];
    const float* Wc1 = (const float*)d_in[8];
    const float* bc1 = (const float*)d_in[9];
    const float* Wc2 = (const float*)d_in[10];
    const float* bc2 = (const float*)d_in[11];
    const float* We1 = (const float*)d_in[12];
    const float* be1 = (const float*)d_in[13];
    const float* We2 = (const float*)d_in[14];
    const float* be2 = (const float*)d_in[15];
    float* out = (float*)d_out;

    const int nV = in_sizes[0] / 32;
    const int nC = in_sizes[1] / 32;
    const int nE = in_sizes[2] / 32;

    unsigned short* pv = (unsigned short*)d_ws;
    unsigned short* pc = pv + (size_t)nV * 32;

    const int wavesV = (((nV + 31) >> 5) + 3) >> 2;
    const int wavesC = (((nC + 31) >> 5) + 3) >> 2;
    const int nodeBlocks = (wavesV + wavesC + 3) / 4;
    nodes_kernel<<<nodeBlocks, 256, 0, stream>>>(
        var_f, con_f, Wv1, bv1, Wv2, bv2, Wc1, bc1, Wc2, bc2,
        We1, be1, pv, pc, nV, nC, wavesV);

    edge_kernel<<<2304, 256, 0, stream>>>(Ef, idx, pv, pc, We1, We2, be2, out, nE);
}

// Round 8
// 158.471 us; speedup vs baseline: 1.6086x; 1.1044x over previous
//
#include <hip/hip_runtime.h>

typedef float  f32x2  __attribute__((ext_vector_type(2)));
typedef float  f32x4  __attribute__((ext_vector_type(4)));
typedef float  f32x16 __attribute__((ext_vector_type(16)));
typedef short  s16x4  __attribute__((ext_vector_type(4)));
typedef short  s16x8  __attribute__((ext_vector_type(8)));
typedef unsigned int u32x2 __attribute__((ext_vector_type(2)));

__device__ __forceinline__ unsigned f2bf(float f) {
    unsigned u = __builtin_bit_cast(unsigned, f);
    u += 0x7FFFu + ((u >> 16) & 1u);   // RNE
    return u >> 16;
}
__device__ __forceinline__ s16x4 pack4(float a, float b, float c, float d) {
    u32x2 u;
    u[0] = f2bf(a) | (f2bf(b) << 16);
    u[1] = f2bf(c) | (f2bf(d) << 16);
    return __builtin_bit_cast(s16x4, u);
}
__device__ __forceinline__ s16x4 pack4v(f32x4 v) { return pack4(v[0], v[1], v[2], v[3]); }
__device__ __forceinline__ s16x4 lo4(s16x8 v) { return __builtin_shufflevector(v, v, 0, 1, 2, 3); }
__device__ __forceinline__ s16x4 hi4(s16x8 v) { return __builtin_shufflevector(v, v, 4, 5, 6, 7); }

// ---------------------------------------------------------------------------
// Node MLP (unchanged from R5, proven): P = relu(relu(X W1^T+b1) W2^T+b2) Wm^T
// (+ bm), bf16 out, natural channel layout P[node*32+ch]. 32x32x8 MFMA path.
// ---------------------------------------------------------------------------
__device__ __forceinline__ void node_body(
    const float* __restrict__ X,
    const float* __restrict__ W1, const float* __restrict__ b1,
    const float* __restrict__ W2, const float* __restrict__ b2,
    const float* __restrict__ Wm, const float* __restrict__ bm,
    unsigned short* __restrict__ outp, int N, int tile0)
{
    const int lane = threadIdx.x & 63;
    const int g = lane >> 5, m = lane & 31;
    const int ntile = (N + 31) >> 5;
    if (tile0 >= ntile) return;

    s16x4 a1[4], a2[4], am[4];
#pragma unroll
    for (int q = 0; q < 4; ++q) {
        const float* p1 = W1 + m * 32 + 8 * q + 4 * g;
        a1[q] = pack4(p1[0], p1[1], p1[2], p1[3]);
        const float* p2 = W2 + m * 32 + 8 * q + 4 * g;
        a2[q] = pack4(p2[0], p2[1], p2[2], p2[3]);
        const float* pm = Wm + m * 96 + 8 * q + 4 * g;
        am[q] = pack4(pm[0], pm[1], pm[2], pm[3]);
    }
    f32x16 f1, f2, f3;
#pragma unroll
    for (int r = 0; r < 16; ++r) {
        int ch = (r & 3) + 8 * (r >> 2) + 4 * g;
        f1[r] = b1[ch];
        f2[r] = b2[ch];
        f3[r] = bm ? bm[ch] : 0.f;
    }

#pragma unroll
    for (int k = 0; k < 4; ++k) {
        const int tile = tile0 + k;
        if (tile >= ntile) break;
        const int node0 = tile * 32 + m;
        const int node = node0 < N ? node0 : N - 1;

        s16x4 bX[4];
#pragma unroll
        for (int q = 0; q < 4; ++q) {
            f32x4 v = *reinterpret_cast<const f32x4*>(X + (size_t)node * 32 + 8 * q + 4 * g);
            bX[q] = pack4v(v);
        }
        f32x16 acc = f1;
#pragma unroll
        for (int q = 0; q < 4; ++q) acc = __builtin_amdgcn_mfma_f32_32x32x8bf16_1k(a1[q], bX[q], acc, 0, 0, 0);
        s16x4 bH[4];
#pragma unroll
        for (int q = 0; q < 4; ++q)
            bH[q] = pack4(fmaxf(acc[4*q+0], 0.f), fmaxf(acc[4*q+1], 0.f),
                          fmaxf(acc[4*q+2], 0.f), fmaxf(acc[4*q+3], 0.f));
        acc = f2;
#pragma unroll
        for (int q = 0; q < 4; ++q) acc = __builtin_amdgcn_mfma_f32_32x32x8bf16_1k(a2[q], bH[q], acc, 0, 0, 0);
#pragma unroll
        for (int q = 0; q < 4; ++q)
            bH[q] = pack4(fmaxf(acc[4*q+0], 0.f), fmaxf(acc[4*q+1], 0.f),
                          fmaxf(acc[4*q+2], 0.f), fmaxf(acc[4*q+3], 0.f));
        acc = f3;
#pragma unroll
        for (int q = 0; q < 4; ++q) acc = __builtin_amdgcn_mfma_f32_32x32x8bf16_1k(am[q], bH[q], acc, 0, 0, 0);

        if (node0 < N) {
#pragma unroll
            for (int q = 0; q < 4; ++q) {
                s16x4 o = pack4(acc[4*q+0], acc[4*q+1], acc[4*q+2], acc[4*q+3]);
                *reinterpret_cast<s16x4*>(outp + (size_t)node0 * 32 + 8 * q + 4 * g) = o;
            }
        }
    }
}

__global__ __launch_bounds__(256) void nodes_kernel(
    const float* __restrict__ var_f, const float* __restrict__ con_f,
    const float* __restrict__ Wv1, const float* __restrict__ bv1,
    const float* __restrict__ Wv2, const float* __restrict__ bv2,
    const float* __restrict__ Wc1, const float* __restrict__ bc1,
    const float* __restrict__ Wc2, const float* __restrict__ bc2,
    const float* __restrict__ We1, const float* __restrict__ be1,
    unsigned short* __restrict__ pv, unsigned short* __restrict__ pc,
    int nV, int nC, int wavesV)
{
    const int wvg = (blockIdx.x * blockDim.x + threadIdx.x) >> 6;
    if (wvg < wavesV) {
        node_body(var_f, Wv1, bv1, Wv2, bv2, We1 + 32, be1, pv, nV, wvg * 4);
    } else {
        node_body(con_f, Wc1, bc1, Wc2, bc2, We1 + 64, nullptr, pc, nC,
                  (wvg - wavesV) * 4);
    }
}

// ---------------------------------------------------------------------------
// Edge kernel, 16x16x16 MFMA, edges-as-COLUMNS. Per 32-edge tile:
//  - Ef B-frags: lane l reads Ef[16e+(l%16)][16kk+4(l/16)..+4): 4 lanes consume
//    one full 64B line -> fully line-coalesced loads (16 lines/instr).
//  - pv/pc: one 16B load per (side,e): lane reads row i0[16e+m] shorts
//    [8c..8c+8) -> 4 lanes per 64B row, full-line gathers. A permutation
//    fragment aP (A[ch][k]=1 iff ch==8c+4kk+j) consumes lo4/hi4 directly.
//  - D(r,e) of layer1 IS layer2's B k-block r for edge-block e (zero shuffle).
//  - depth-1 pipeline identical to R5; LDS transpose stores; NT writes.
// ---------------------------------------------------------------------------
__global__ __launch_bounds__(256, 4) void edge_kernel(
    const float* __restrict__ Ef, const int* __restrict__ idx,
    const unsigned short* __restrict__ pv, const unsigned short* __restrict__ pc,
    const float* __restrict__ We1, const float* __restrict__ We2,
    const float* __restrict__ be2,
    float* __restrict__ out, int nE)
{
    __shared__ float ldso[4 * 1088];          // 4 waves * 32 rows * stride 34
    const int lane = threadIdx.x & 63;
    const int wv = threadIdx.x >> 6;
    const int m = lane & 15, c = lane >> 4;   // 16x16 frag coords
    float* ldsw = ldso + wv * 1088;

    // Weight fragments (16x16x16): A[row=l%16][k=4c+j].
    s16x4 aW1[2][2], aP[2][2], aW2[2][2];
    f32x4 b2f[2];
#pragma unroll
    for (int r = 0; r < 2; ++r) {
#pragma unroll
        for (int kk = 0; kk < 2; ++kk) {
            const float* p1 = We1 + (16 * r + m) * 96 + 16 * kk + 4 * c;
            aW1[r][kk] = pack4(p1[0], p1[1], p1[2], p1[3]);
            const float* p2 = We2 + (16 * r + m) * 32 + 16 * kk + 4 * c;
            aW2[r][kk] = pack4(p2[0], p2[1], p2[2], p2[3]);
            const int j_hit = 16 * r + m - 8 * c - 4 * kk;
            s16x4 w;
#pragma unroll
            for (int j = 0; j < 4; ++j) w[j] = (short)((j == j_hit) ? 0x3F80 : 0);
            aP[r][kk] = w;
        }
        f32x4 b;
#pragma unroll
        for (int j = 0; j < 4; ++j) b[j] = be2[16 * r + 4 * c + j];
        b2f[r] = b;
    }

    const int ntile = nE >> 5;
    const int nw = (gridDim.x * blockDim.x) >> 6;
    int t = (blockIdx.x * blockDim.x + threadIdx.x) >> 6;
    if (t >= ntile) return;

    // ---- prologue: stage tile t ----
    int ib0[2], ib1[2];          // idx for the NEXT staged tile
    s16x4 ebf[2][2];             // Ef bf16 frags, current tile
    s16x8 pvf[2], pcf[2];        // gathered partials, current tile
    {
        int i0[2], i1[2];
#pragma unroll
        for (int e = 0; e < 2; ++e) {
            i0[e] = idx[t * 32 + 16 * e + m];
            i1[e] = idx[nE + t * 32 + 16 * e + m];
        }
#pragma unroll
        for (int e = 0; e < 2; ++e) {
#pragma unroll
            for (int kk = 0; kk < 2; ++kk) {
                f32x4 v = *reinterpret_cast<const f32x4*>(
                    Ef + (size_t)(t * 32 + 16 * e + m) * 32 + 16 * kk + 4 * c);
                ebf[e][kk] = pack4v(v);
            }
            pvf[e] = *reinterpret_cast<const s16x8*>(pv + (size_t)i0[e] * 32 + 8 * c);
            pcf[e] = *reinterpret_cast<const s16x8*>(pc + (size_t)i1[e] * 32 + 8 * c);
        }
        int t1 = (t + nw < ntile) ? t + nw : t;
#pragma unroll
        for (int e = 0; e < 2; ++e) {
            ib0[e] = idx[t1 * 32 + 16 * e + m];
            ib1[e] = idx[nE + t1 * 32 + 16 * e + m];
        }
    }

    while (true) {
        const int tn = t + nw;
        const int tc = tn < ntile ? tn : t;

        // ---- issue stage(t+nw): Ef (f32), gathers, idx(t+2nw) ----
        f32x4 nef[2][2];
        s16x8 npv[2], npc[2];
        int ic0[2], ic1[2];
#pragma unroll
        for (int e = 0; e < 2; ++e) {
#pragma unroll
            for (int kk = 0; kk < 2; ++kk)
                nef[e][kk] = *reinterpret_cast<const f32x4*>(
                    Ef + (size_t)(tc * 32 + 16 * e + m) * 32 + 16 * kk + 4 * c);
            npv[e] = *reinterpret_cast<const s16x8*>(pv + (size_t)ib0[e] * 32 + 8 * c);
            npc[e] = *reinterpret_cast<const s16x8*>(pc + (size_t)ib1[e] * 32 + 8 * c);
        }
        {
            int t2 = (tn + nw < ntile) ? tn + nw : tc;
#pragma unroll
            for (int e = 0; e < 2; ++e) {
                ic0[e] = idx[t2 * 32 + 16 * e + m];
                ic1[e] = idx[nE + t2 * 32 + 16 * e + m];
            }
        }

        // ---- layer 1: acc[r][e], K=96 (Ef 2kk + pv perm + pc perm) ----
        f32x4 a00 = {}, a01 = {}, a10 = {}, a11 = {};
        a00 = __builtin_amdgcn_mfma_f32_16x16x16bf16_1k(aW1[0][0], ebf[0][0], a00, 0, 0, 0);
        a01 = __builtin_amdgcn_mfma_f32_16x16x16bf16_1k(aW1[0][0], ebf[1][0], a01, 0, 0, 0);
        a10 = __builtin_amdgcn_mfma_f32_16x16x16bf16_1k(aW1[1][0], ebf[0][0], a10, 0, 0, 0);
        a11 = __builtin_amdgcn_mfma_f32_16x16x16bf16_1k(aW1[1][0], ebf[1][0], a11, 0, 0, 0);
        a00 = __builtin_amdgcn_mfma_f32_16x16x16bf16_1k(aW1[0][1], ebf[0][1], a00, 0, 0, 0);
        a01 = __builtin_amdgcn_mfma_f32_16x16x16bf16_1k(aW1[0][1], ebf[1][1], a01, 0, 0, 0);
        a10 = __builtin_amdgcn_mfma_f32_16x16x16bf16_1k(aW1[1][1], ebf[0][1], a10, 0, 0, 0);
        a11 = __builtin_amdgcn_mfma_f32_16x16x16bf16_1k(aW1[1][1], ebf[1][1], a11, 0, 0, 0);
        a00 = __builtin_amdgcn_mfma_f32_16x16x16bf16_1k(aP[0][0], lo4(pvf[0]), a00, 0, 0, 0);
        a00 = __builtin_amdgcn_mfma_f32_16x16x16bf16_1k(aP[0][1], hi4(pvf[0]), a00, 0, 0, 0);
        a01 = __builtin_amdgcn_mfma_f32_16x16x16bf16_1k(aP[0][0], lo4(pvf[1]), a01, 0, 0, 0);
        a01 = __builtin_amdgcn_mfma_f32_16x16x16bf16_1k(aP[0][1], hi4(pvf[1]), a01, 0, 0, 0);
        a10 = __builtin_amdgcn_mfma_f32_16x16x16bf16_1k(aP[1][0], lo4(pvf[0]), a10, 0, 0, 0);
        a10 = __builtin_amdgcn_mfma_f32_16x16x16bf16_1k(aP[1][1], hi4(pvf[0]), a10, 0, 0, 0);
        a11 = __builtin_amdgcn_mfma_f32_16x16x16bf16_1k(aP[1][0], lo4(pvf[1]), a11, 0, 0, 0);
        a11 = __builtin_amdgcn_mfma_f32_16x16x16bf16_1k(aP[1][1], hi4(pvf[1]), a11, 0, 0, 0);
        a00 = __builtin_amdgcn_mfma_f32_16x16x16bf16_1k(aP[0][0], lo4(pcf[0]), a00, 0, 0, 0);
        a00 = __builtin_amdgcn_mfma_f32_16x16x16bf16_1k(aP[0][1], hi4(pcf[0]), a00, 0, 0, 0);
        a01 = __builtin_amdgcn_mfma_f32_16x16x16bf16_1k(aP[0][0], lo4(pcf[1]), a01, 0, 0, 0);
        a01 = __builtin_amdgcn_mfma_f32_16x16x16bf16_1k(aP[0][1], hi4(pcf[1]), a01, 0, 0, 0);
        a10 = __builtin_amdgcn_mfma_f32_16x16x16bf16_1k(aP[1][0], lo4(pcf[0]), a10, 0, 0, 0);
        a10 = __builtin_amdgcn_mfma_f32_16x16x16bf16_1k(aP[1][1], hi4(pcf[0]), a10, 0, 0, 0);
        a11 = __builtin_amdgcn_mfma_f32_16x16x16bf16_1k(aP[1][0], lo4(pcf[1]), a11, 0, 0, 0);
        a11 = __builtin_amdgcn_mfma_f32_16x16x16bf16_1k(aP[1][1], hi4(pcf[1]), a11, 0, 0, 0);

        // ---- relu + pack: bH[e][kk] <- acc[r=kk][e] ----
        s16x4 bH00 = pack4(fmaxf(a00[0], 0.f), fmaxf(a00[1], 0.f), fmaxf(a00[2], 0.f), fmaxf(a00[3], 0.f));
        s16x4 bH01 = pack4(fmaxf(a10[0], 0.f), fmaxf(a10[1], 0.f), fmaxf(a10[2], 0.f), fmaxf(a10[3], 0.f));
        s16x4 bH10 = pack4(fmaxf(a01[0], 0.f), fmaxf(a01[1], 0.f), fmaxf(a01[2], 0.f), fmaxf(a01[3], 0.f));
        s16x4 bH11 = pack4(fmaxf(a11[0], 0.f), fmaxf(a11[1], 0.f), fmaxf(a11[2], 0.f), fmaxf(a11[3], 0.f));

        // ---- layer 2: o[r][e] = be2 + We2 * H ----
        f32x4 o00 = b2f[0], o01 = b2f[0], o10 = b2f[1], o11 = b2f[1];
        o00 = __builtin_amdgcn_mfma_f32_16x16x16bf16_1k(aW2[0][0], bH00, o00, 0, 0, 0);
        o01 = __builtin_amdgcn_mfma_f32_16x16x16bf16_1k(aW2[0][0], bH10, o01, 0, 0, 0);
        o10 = __builtin_amdgcn_mfma_f32_16x16x16bf16_1k(aW2[1][0], bH00, o10, 0, 0, 0);
        o11 = __builtin_amdgcn_mfma_f32_16x16x16bf16_1k(aW2[1][0], bH10, o11, 0, 0, 0);
        o00 = __builtin_amdgcn_mfma_f32_16x16x16bf16_1k(aW2[0][1], bH01, o00, 0, 0, 0);
        o01 = __builtin_amdgcn_mfma_f32_16x16x16bf16_1k(aW2[0][1], bH11, o01, 0, 0, 0);
        o10 = __builtin_amdgcn_mfma_f32_16x16x16bf16_1k(aW2[1][1], bH01, o10, 0, 0, 0);
        o11 = __builtin_amdgcn_mfma_f32_16x16x16bf16_1k(aW2[1][1], bH11, o11, 0, 0, 0);

        // ---- store: LDS transpose (stride 34), then coalesced NT stores ----
        {
#pragma unroll
            for (int r = 0; r < 2; ++r) {
#pragma unroll
                for (int e = 0; e < 2; ++e) {
                    f32x4 o = (r == 0) ? (e == 0 ? o00 : o01) : (e == 0 ? o10 : o11);
                    float* p = ldsw + (size_t)(16 * e + m) * 34 + 16 * r + 4 * c;
                    f32x2 lo; lo[0] = o[0]; lo[1] = o[1];
                    f32x2 hi; hi[0] = o[2]; hi[1] = o[3];
                    *reinterpret_cast<f32x2*>(p)     = lo;
                    *reinterpret_cast<f32x2*>(p + 2) = hi;
                }
            }
            float* obase = out + (size_t)t * 1024;
#pragma unroll
            for (int p = 0; p < 4; ++p) {
                int li = p * 256 + lane * 4;
                int row = li >> 5, col = li & 31;
                const float* s = ldsw + (size_t)row * 34 + col;
                f32x2 lo = *reinterpret_cast<const f32x2*>(s);
                f32x2 hi = *reinterpret_cast<const f32x2*>(s + 2);
                f32x4 v; v[0] = lo[0]; v[1] = lo[1]; v[2] = hi[0]; v[3] = hi[1];
                __builtin_nontemporal_store(v, reinterpret_cast<f32x4*>(obase + li));
            }
        }

        if (tn >= ntile) break;
        t = tn;
#pragma unroll
        for (int e = 0; e < 2; ++e) {
#pragma unroll
            for (int kk = 0; kk < 2; ++kk) ebf[e][kk] = pack4v(nef[e][kk]);
            pvf[e] = npv[e]; pcf[e] = npc[e];
            ib0[e] = ic0[e]; ib1[e] = ic1[e];
        }
    }
}

extern "C" void kernel_launch(void* const* d_in, const int* in_sizes, int n_in,
                              void* d_out, int out_size, void* d_ws, size_t ws_size,
                              hipStream_t stream) {
    const float* var_f = (const float*)d_in[0];
    const float* con_f = (const float*)d_in[1];
    const float* Ef    = (const float*)d_in[2];
    const int*   idx   = (const int*)d_in[3];
    const float* Wv1 = (const float*)d_in[4];
    const float* bv1 = (const float*)d_in[5];
    const float* Wv2 = (const float*)d_in[6];
    const float* bv2 = (const float*)d_in[7];
    const float* Wc1 = (const float*)d_in[8];
    const float* bc1 = (const float*)d_in[9];
    const float* Wc2 = (const float*)d_in[10];
    const float* bc2 = (const float*)d_in[11];
    const float* We1 = (const float*)d_in[12];
    const float* be1 = (const float*)d_in[13];
    const float* We2 = (const float*)d_in[14];
    const float* be2 = (const float*)d_in[15];
    float* out = (float*)d_out;

    const int nV = in_sizes[0] / 32;
    const int nC = in_sizes[1] / 32;
    const int nE = in_sizes[2] / 32;

    unsigned short* pv = (unsigned short*)d_ws;
    unsigned short* pc = pv + (size_t)nV * 32;

    const int wavesV = (((nV + 31) >> 5) + 3) >> 2;
    const int wavesC = (((nC + 31) >> 5) + 3) >> 2;
    const int nodeBlocks = (wavesV + wavesC + 3) / 4;
    nodes_kernel<<<nodeBlocks, 256, 0, stream>>>(
        var_f, con_f, Wv1, bv1, Wv2, bv2, Wc1, bc1, Wc2, bc2,
        We1, be1, pv, pc, nV, nC, wavesV);

    edge_kernel<<<1024, 256, 0, stream>>>(Ef, idx, pv, pc, We1, We2, be2, out, nE);
}